// Round 6
// baseline (558.519 us; speedup 1.0000x reference)
//
#include <hip/hip_runtime.h>
#include <math.h>

#define N_NODES 100000
#define N_EDGES 1600000
#define HID 32
#define BN_EPS 1e-3f
#define NB 3125          // buckets of 32 nodes: 3125*32 = 100000 exactly

__device__ __forceinline__ float eluf(float x) { return x > 0.f ? x : expm1f(x); }

__device__ __forceinline__ float wave_sum64(float v) {
#pragma unroll
    for (int off = 32; off > 0; off >>= 1) v += __shfl_xor(v, off, 64);
    return v;
}

// monotonic order-preserving encode float -> uint (0 = unreachable sentinel for finite inputs)
__device__ __forceinline__ unsigned int encf(float f) {
    unsigned int u = __float_as_uint(f);
    return (u & 0x80000000u) ? ~u : (u | 0x80000000u);
}
__device__ __forceinline__ float decf(unsigned int k) {
    return __uint_as_float((k & 0x80000000u) ? (k & 0x7FFFFFFFu) : ~k);
}

// ---------------- kernel 1: node encoder + BN1 partial stats ----------------
__global__ __launch_bounds__(256) void k_encode(
    const float* __restrict__ x_cont, const int* __restrict__ x_cat,
    const float* __restrict__ datanorm,
    const float* __restrict__ W_cont, const float* __restrict__ b_cont,
    const float* __restrict__ emb_charge, const float* __restrict__ emb_pdg,
    const float* __restrict__ W_cat, const float* __restrict__ b_cat,
    const float* __restrict__ W_enc, const float* __restrict__ b_enc,
    float* __restrict__ emb_out, float* __restrict__ sum1, float* __restrict__ sumsq1)
{
    __shared__ __align__(16) float sWc[6 * 16];
    __shared__ __align__(16) float sWcat[16 * 16];
    __shared__ __align__(16) float sWenc[32 * 32];
    __shared__ __align__(16) float sbc[16];
    __shared__ __align__(16) float sbcat[16];
    __shared__ __align__(16) float sbenc[32];
    __shared__ float sdn[6], sech[3 * 8], sepd[7 * 8];
    __shared__ float ps[4][32], pq[4][32];

    int tid = threadIdx.x;
    for (int t = tid; t < 96; t += 256) sWc[t] = W_cont[t];
    for (int t = tid; t < 256; t += 256) sWcat[t] = W_cat[t];
    for (int t = tid; t < 1024; t += 256) sWenc[t] = W_enc[t];
    if (tid < 16) { sbc[tid] = b_cont[tid]; sbcat[tid] = b_cat[tid]; }
    if (tid < 32) sbenc[tid] = b_enc[tid];
    if (tid < 6)  sdn[tid] = datanorm[tid];
    if (tid < 24) sech[tid] = emb_charge[tid];
    if (tid < 56) sepd[tid] = emb_pdg[tid];
    __syncthreads();

    int n = blockIdx.x * 256 + tid;
    float e[32];
    if (n < N_NODES) {
        float xc[6];
#pragma unroll
        for (int i = 0; i < 6; i++) xc[i] = x_cont[n * 6 + i] * sdn[i];

        float cont[16];
        {
            const float4* W4 = (const float4*)sWc;
            const float4* b4 = (const float4*)sbc;
#pragma unroll
            for (int j4 = 0; j4 < 4; j4++) {
                float4 acc = b4[j4];
#pragma unroll
                for (int i = 0; i < 6; i++) {
                    float4 w = W4[i * 4 + j4];
                    acc.x += xc[i] * w.x; acc.y += xc[i] * w.y;
                    acc.z += xc[i] * w.z; acc.w += xc[i] * w.w;
                }
                cont[j4 * 4 + 0] = eluf(acc.x); cont[j4 * 4 + 1] = eluf(acc.y);
                cont[j4 * 4 + 2] = eluf(acc.z); cont[j4 * 4 + 3] = eluf(acc.w);
            }
        }

        int pdg = x_cat[n * 2 + 0], chg = x_cat[n * 2 + 1];
        int p = pdg < 0 ? -pdg : pdg;
        int pidx;
        switch (p) {
            case 1: pidx = 0; break; case 2: pidx = 1; break;
            case 11: pidx = 2; break; case 13: pidx = 3; break;
            case 22: pidx = 4; break; case 130: pidx = 5; break;
            case 211: pidx = 6; break; default: pidx = 0; break;
        }
        float cin[16];
#pragma unroll
        for (int k = 0; k < 8; k++) cin[k] = sech[(chg + 1) * 8 + k];
#pragma unroll
        for (int k = 0; k < 8; k++) cin[8 + k] = sepd[pidx * 8 + k];

        float cat[16];
        {
            const float4* W4 = (const float4*)sWcat;
            const float4* b4 = (const float4*)sbcat;
#pragma unroll
            for (int j4 = 0; j4 < 4; j4++) {
                float4 acc = b4[j4];
#pragma unroll
                for (int i = 0; i < 16; i++) {
                    float4 w = W4[i * 4 + j4];
                    acc.x += cin[i] * w.x; acc.y += cin[i] * w.y;
                    acc.z += cin[i] * w.z; acc.w += cin[i] * w.w;
                }
                cat[j4 * 4 + 0] = eluf(acc.x); cat[j4 * 4 + 1] = eluf(acc.y);
                cat[j4 * 4 + 2] = eluf(acc.z); cat[j4 * 4 + 3] = eluf(acc.w);
            }
        }

        float in32[32];
#pragma unroll
        for (int k = 0; k < 16; k++) { in32[k] = cat[k]; in32[16 + k] = cont[k]; }

        {
            const float4* W4 = (const float4*)sWenc;
            const float4* b4 = (const float4*)sbenc;
#pragma unroll
            for (int j4 = 0; j4 < 8; j4++) {
                float4 acc = b4[j4];
#pragma unroll
                for (int i = 0; i < 32; i++) {
                    float4 w = W4[i * 8 + j4];
                    acc.x += in32[i] * w.x; acc.y += in32[i] * w.y;
                    acc.z += in32[i] * w.z; acc.w += in32[i] * w.w;
                }
                e[j4 * 4 + 0] = eluf(acc.x); e[j4 * 4 + 1] = eluf(acc.y);
                e[j4 * 4 + 2] = eluf(acc.z); e[j4 * 4 + 3] = eluf(acc.w);
            }
        }
        float4* out4 = (float4*)(emb_out + (size_t)n * 32);
#pragma unroll
        for (int j4 = 0; j4 < 8; j4++)
            out4[j4] = make_float4(e[j4 * 4 + 0], e[j4 * 4 + 1], e[j4 * 4 + 2], e[j4 * 4 + 3]);
    } else {
#pragma unroll
        for (int j = 0; j < 32; j++) e[j] = 0.f;
    }

    // BN1 partial stats
    int lane = tid & 63, wid = tid >> 6;
#pragma unroll
    for (int c = 0; c < 32; c++) {
        float s = wave_sum64(e[c]);
        float q = wave_sum64(e[c] * e[c]);
        if (lane == 0) { ps[wid][c] = s; pq[wid][c] = q; }
    }
    __syncthreads();
    if (tid < 32) {
        atomicAdd(&sum1[tid], ps[0][tid] + ps[1][tid] + ps[2][tid] + ps[3][tid]);
        atomicAdd(&sumsq1[tid], pq[0][tid] + pq[1][tid] + pq[2][tid] + pq[3][tid]);
    }
}

// ---------------- kernel 2: finalize BN stats ----------------
__global__ void k_finalize(const float* __restrict__ sum, const float* __restrict__ sumsq,
                           float* __restrict__ mean, float* __restrict__ istd)
{
    int c = threadIdx.x;
    if (c < 32) {
        float m = sum[c] / (float)N_NODES;
        float v = sumsq[c] / (float)N_NODES - m * m;
        mean[c] = m;
        istd[c] = 1.0f / sqrtf(v + BN_EPS);
    }
}

// ---------------- kernel 3: apply BN1, compute A = e@(W0-W1), B = e@W1 ----------------
__global__ __launch_bounds__(256) void k_normAB(
    float* __restrict__ emb,           // in: pre-BN, out: normalized (in place)
    const float* __restrict__ W_msg,
    const float* __restrict__ g, const float* __restrict__ be,
    const float* __restrict__ mean, const float* __restrict__ istd,
    float* __restrict__ A, float* __restrict__ B)
{
    __shared__ __align__(16) float sWA[32 * 32];
    __shared__ __align__(16) float sWB[32 * 32];
    __shared__ float sg[32], sb[32], sm[32], si[32];
    int tid = threadIdx.x;
    for (int t = tid; t < 1024; t += 256) {
        float w0 = W_msg[t];
        float w1 = W_msg[1024 + t];
        sWA[t] = w0 - w1;
        sWB[t] = w1;
    }
    if (tid < 32) { sg[tid] = g[tid]; sb[tid] = be[tid]; sm[tid] = mean[tid]; si[tid] = istd[tid]; }
    __syncthreads();

    int n = blockIdx.x * 256 + tid;
    if (n >= N_NODES) return;

    float e[32];
    float4* base4 = (float4*)(emb + (size_t)n * 32);
#pragma unroll
    for (int j4 = 0; j4 < 8; j4++) {
        float4 v = base4[j4];
        e[j4 * 4 + 0] = v.x; e[j4 * 4 + 1] = v.y; e[j4 * 4 + 2] = v.z; e[j4 * 4 + 3] = v.w;
    }
#pragma unroll
    for (int j = 0; j < 32; j++) e[j] = sg[j] * (e[j] - sm[j]) * si[j] + sb[j];
#pragma unroll
    for (int j4 = 0; j4 < 8; j4++)
        base4[j4] = make_float4(e[j4 * 4 + 0], e[j4 * 4 + 1], e[j4 * 4 + 2], e[j4 * 4 + 3]);

    float a[32], bb[32];
#pragma unroll
    for (int j = 0; j < 32; j++) { a[j] = 0.f; bb[j] = 0.f; }
    const float4* WA4 = (const float4*)sWA;
    const float4* WB4 = (const float4*)sWB;
#pragma unroll
    for (int i = 0; i < 32; i++) {
        float x = e[i];
#pragma unroll
        for (int j4 = 0; j4 < 8; j4++) {
            float4 wa = WA4[i * 8 + j4];
            float4 wb = WB4[i * 8 + j4];
            a[j4 * 4 + 0] += x * wa.x; a[j4 * 4 + 1] += x * wa.y;
            a[j4 * 4 + 2] += x * wa.z; a[j4 * 4 + 3] += x * wa.w;
            bb[j4 * 4 + 0] += x * wb.x; bb[j4 * 4 + 1] += x * wb.y;
            bb[j4 * 4 + 2] += x * wb.z; bb[j4 * 4 + 3] += x * wb.w;
        }
    }
    float4* A4 = (float4*)(A + (size_t)n * 32);
    float4* B4 = (float4*)(B + (size_t)n * 32);
#pragma unroll
    for (int j4 = 0; j4 < 8; j4++) {
        A4[j4] = make_float4(a[j4 * 4 + 0], a[j4 * 4 + 1], a[j4 * 4 + 2], a[j4 * 4 + 3]);
        B4[j4] = make_float4(bb[j4 * 4 + 0], bb[j4 * 4 + 1], bb[j4 * 4 + 2], bb[j4 * 4 + 3]);
    }
}

// ---------------- kernel 4a: per-bucket edge histogram (3125 counters, L2-hot) ------
__global__ __launch_bounds__(256) void k_hist(const int* __restrict__ dst, int* __restrict__ bcount)
{
    int e = blockIdx.x * 256 + threadIdx.x;
    if (e < N_EDGES) atomicAdd(&bcount[dst[e] >> 5], 1);
}

// ---------------- kernel 4b: single-block scan of 3125 bucket counts ----------------
__global__ __launch_bounds__(1024) void k_bscan(const int* __restrict__ bcount,
                                                int* __restrict__ boff, int* __restrict__ bcur)
{
    __shared__ int s[1024];
    int t = threadIdx.x;
    int c[4]; int sum = 0;
#pragma unroll
    for (int i = 0; i < 4; i++) {
        int idx = t * 4 + i;
        c[i] = (idx < NB) ? bcount[idx] : 0;
        sum += c[i];
    }
    s[t] = sum;
    __syncthreads();
#pragma unroll
    for (int o = 1; o < 1024; o <<= 1) {
        int u = (t >= o) ? s[t - o] : 0;
        __syncthreads();
        s[t] += u;
        __syncthreads();
    }
    int run = s[t] - sum;  // exclusive prefix for this thread's chunk
#pragma unroll
    for (int i = 0; i < 4; i++) {
        int idx = t * 4 + i;
        if (idx < NB) { boff[idx] = run; bcur[idx] = run; run += c[i]; }
    }
    if (t == 1023) boff[NB] = s[1023];
}

// ---------------- kernel 4c: scatter packed (dst_local<<27 | src) into bucket ranges --
// Concurrent appends to a bucket hit adjacent positions -> L2 line coalescing.
__global__ __launch_bounds__(256) void k_scatter(const int* __restrict__ src, const int* __restrict__ dst,
                                                 int* __restrict__ bcur, int* __restrict__ eidx)
{
    int e = blockIdx.x * 256 + threadIdx.x;
    if (e < N_EDGES) {
        int d = dst[e];
        int pos = atomicAdd(&bcur[d >> 5], 1);
        eidx[pos] = ((d & 31) << 27) | src[e];
    }
}

// ---------------- kernel 5: per-bucket LDS-atomic segment max + agg + BN2 stats -------
// One block per bucket (32 nodes). 8 lanes/edge, 4 channels/lane.
__global__ __launch_bounds__(256) void k_bucket_agg(
    const int* __restrict__ boff, const int* __restrict__ eidx,
    const float* __restrict__ B,
    float* __restrict__ A,             // in: A, out: agg (in place)
    const float* __restrict__ b_msg,
    float* __restrict__ sum2, float* __restrict__ sumsq2)
{
    __shared__ unsigned int smax[32 * 33];   // [node][ch], stride 33 breaks bank aliasing
    __shared__ float sb[32];
    __shared__ float ps[4][32], pq[4][32];
    int tid = threadIdx.x;
    if (tid < 32) sb[tid] = b_msg[tid];
    for (int i = tid; i < 32 * 33; i += 256) smax[i] = 0u;
    __syncthreads();

    int b = blockIdx.x;
    int bstart = boff[b], bend = boff[b + 1];
    int slot = tid >> 3;      // 32 edge slots per iteration
    int sub  = tid & 7;       // channels 4*sub .. 4*sub+3

    for (int k = bstart + slot; k < bend; k += 32) {
        unsigned int v = (unsigned int)eidx[k];
        int s  = (int)(v & 0x07FFFFFFu);
        int dl = (int)(v >> 27);
        float4 bv = *(const float4*)(B + (size_t)s * 32 + sub * 4);
        unsigned int* row = &smax[dl * 33 + sub * 4];
        atomicMax(row + 0, encf(bv.x));
        atomicMax(row + 1, encf(bv.y));
        atomicMax(row + 2, encf(bv.z));
        atomicMax(row + 3, encf(bv.w));
    }
    __syncthreads();

    // finalize: 32 nodes x 8 channel-groups = 256 threads
    int grp = tid >> 3;
    int n = b * 32 + grp;     // N = 3125*32 exactly, always in range
    unsigned int k0 = smax[grp * 33 + sub * 4 + 0];
    unsigned int k1 = smax[grp * 33 + sub * 4 + 1];
    unsigned int k2 = smax[grp * 33 + sub * 4 + 2];
    unsigned int k3 = smax[grp * 33 + sub * 4 + 3];

    float4* arow = (float4*)(A + (size_t)n * 32 + sub * 4);
    float4 a = *arow;
    float4 agg;
    agg.x = k0 ? (decf(k0) + a.x + sb[sub * 4 + 0]) : 0.f;
    agg.y = k1 ? (decf(k1) + a.y + sb[sub * 4 + 1]) : 0.f;
    agg.z = k2 ? (decf(k2) + a.z + sb[sub * 4 + 2]) : 0.f;
    agg.w = k3 ? (decf(k3) + a.w + sb[sub * 4 + 3]) : 0.f;
    *arow = agg;

    // BN2 partial stats: sum over the 8 nodes in each wave per channel group.
    float s0 = agg.x, s1 = agg.y, s2 = agg.z, s3 = agg.w;
    float q0 = agg.x * agg.x, q1 = agg.y * agg.y, q2 = agg.z * agg.z, q3 = agg.w * agg.w;
#pragma unroll
    for (int o = 8; o < 64; o <<= 1) {
        s0 += __shfl_xor(s0, o, 64); s1 += __shfl_xor(s1, o, 64);
        s2 += __shfl_xor(s2, o, 64); s3 += __shfl_xor(s3, o, 64);
        q0 += __shfl_xor(q0, o, 64); q1 += __shfl_xor(q1, o, 64);
        q2 += __shfl_xor(q2, o, 64); q3 += __shfl_xor(q3, o, 64);
    }
    int lane = tid & 63, wid = tid >> 6;
    if (lane < 8) {
        ps[wid][lane * 4 + 0] = s0; ps[wid][lane * 4 + 1] = s1;
        ps[wid][lane * 4 + 2] = s2; ps[wid][lane * 4 + 3] = s3;
        pq[wid][lane * 4 + 0] = q0; pq[wid][lane * 4 + 1] = q1;
        pq[wid][lane * 4 + 2] = q2; pq[wid][lane * 4 + 3] = q3;
    }
    __syncthreads();
    if (tid < 32) {
        atomicAdd(&sum2[tid], ps[0][tid] + ps[1][tid] + ps[2][tid] + ps[3][tid]);
        atomicAdd(&sumsq2[tid], pq[0][tid] + pq[1][tid] + pq[2][tid] + pq[3][tid]);
    }
}

// ---------------- kernel 6: residual + BN2 + output head ----------------
__global__ __launch_bounds__(256) void k_out(
    const float* __restrict__ emb, const float* __restrict__ agg,
    const float* __restrict__ g, const float* __restrict__ be,
    const float* __restrict__ mean, const float* __restrict__ istd,
    const float* __restrict__ W_o1, const float* __restrict__ b_o1,
    const float* __restrict__ W_o2, const float* __restrict__ b_o2,
    float* __restrict__ out)
{
    __shared__ __align__(16) float sW1[32 * 16];
    __shared__ __align__(16) float sb1[16];
    __shared__ float sW2[16], sg[32], sbe[32], sm[32], si[32];
    __shared__ float sb2;
    int tid = threadIdx.x;
    for (int t = tid; t < 512; t += 256) sW1[t] = W_o1[t];
    if (tid < 16) { sW2[tid] = W_o2[tid]; sb1[tid] = b_o1[tid]; }
    if (tid < 32) { sg[tid] = g[tid]; sbe[tid] = be[tid]; sm[tid] = mean[tid]; si[tid] = istd[tid]; }
    if (tid == 0) sb2 = b_o2[0];
    __syncthreads();

    int n = blockIdx.x * 256 + tid;
    if (n >= N_NODES) return;

    float h[32];
    const float4* e4 = (const float4*)(emb + (size_t)n * 32);
    const float4* a4 = (const float4*)(agg + (size_t)n * 32);
#pragma unroll
    for (int j4 = 0; j4 < 8; j4++) {
        float4 ev = e4[j4];
        float4 av = a4[j4];
        h[j4 * 4 + 0] = ev.x + sg[j4 * 4 + 0] * (av.x - sm[j4 * 4 + 0]) * si[j4 * 4 + 0] + sbe[j4 * 4 + 0];
        h[j4 * 4 + 1] = ev.y + sg[j4 * 4 + 1] * (av.y - sm[j4 * 4 + 1]) * si[j4 * 4 + 1] + sbe[j4 * 4 + 1];
        h[j4 * 4 + 2] = ev.z + sg[j4 * 4 + 2] * (av.z - sm[j4 * 4 + 2]) * si[j4 * 4 + 2] + sbe[j4 * 4 + 2];
        h[j4 * 4 + 3] = ev.w + sg[j4 * 4 + 3] * (av.w - sm[j4 * 4 + 3]) * si[j4 * 4 + 3] + sbe[j4 * 4 + 3];
    }

    float o1[16];
    const float4* W14 = (const float4*)sW1;
    const float4* b14 = (const float4*)sb1;
#pragma unroll
    for (int j4 = 0; j4 < 4; j4++) {
        float4 acc = b14[j4];
#pragma unroll
        for (int i = 0; i < 32; i++) {
            float4 w = W14[i * 4 + j4];
            acc.x += h[i] * w.x; acc.y += h[i] * w.y;
            acc.z += h[i] * w.z; acc.w += h[i] * w.w;
        }
        o1[j4 * 4 + 0] = eluf(acc.x); o1[j4 * 4 + 1] = eluf(acc.y);
        o1[j4 * 4 + 2] = eluf(acc.z); o1[j4 * 4 + 3] = eluf(acc.w);
    }
    float o = sb2;
#pragma unroll
    for (int k = 0; k < 16; k++) o += o1[k] * sW2[k];
    out[n] = o;
}

extern "C" void kernel_launch(void* const* d_in, const int* in_sizes, int n_in,
                              void* d_out, int out_size, void* d_ws, size_t ws_size,
                              hipStream_t stream)
{
    const float* x_cont     = (const float*)d_in[0];
    const int*   x_cat      = (const int*)d_in[1];
    const int*   edge_index = (const int*)d_in[2];
    // d_in[3] = batch (unused by reference)
    const float* datanorm   = (const float*)d_in[4];
    const float* W_cont     = (const float*)d_in[5];
    const float* b_cont     = (const float*)d_in[6];
    const float* emb_charge = (const float*)d_in[7];
    const float* emb_pdg    = (const float*)d_in[8];
    const float* W_cat      = (const float*)d_in[9];
    const float* b_cat      = (const float*)d_in[10];
    const float* W_enc      = (const float*)d_in[11];
    const float* b_enc      = (const float*)d_in[12];
    const float* g_all      = (const float*)d_in[13];
    const float* be_all     = (const float*)d_in[14];
    const float* W_msg      = (const float*)d_in[15];
    const float* b_msg      = (const float*)d_in[16];
    const float* g_conv     = (const float*)d_in[17];
    const float* be_conv    = (const float*)d_in[18];
    const float* W_o1       = (const float*)d_in[19];
    const float* b_o1       = (const float*)d_in[20];
    const float* W_o2       = (const float*)d_in[21];
    const float* b_o2       = (const float*)d_in[22];

    const size_t NH = (size_t)N_NODES * 32;
    float* buf_emb = (float*)d_ws;                 // NH floats
    float* buf_A   = buf_emb + NH;                 // NH floats
    float* buf_B   = buf_A + NH;                   // NH floats
    float* stats   = buf_B + NH;                   // 256 floats
    int*   bcount  = (int*)(stats + 256);          // NB
    int*   boff    = bcount + NB;                  // NB+1
    int*   bcur    = boff + NB + 1;                // NB
    int*   eidx    = bcur + NB;                    // E

    float* sum1 = stats,       *sumsq1 = stats + 32, *mean1 = stats + 64,  *istd1 = stats + 96;
    float* sum2 = stats + 128, *sumsq2 = stats + 160, *mean2 = stats + 192, *istd2 = stats + 224;

    hipMemsetAsync(stats, 0, 256 * sizeof(float), stream);
    hipMemsetAsync(bcount, 0, NB * sizeof(int), stream);

    const int* src = edge_index;
    const int* dst = edge_index + N_EDGES;

    int nb = (N_NODES + 255) / 256;
    int eb = N_EDGES / 256;  // 6250 exact

    k_encode<<<nb, 256, 0, stream>>>(x_cont, x_cat, datanorm, W_cont, b_cont,
                                     emb_charge, emb_pdg, W_cat, b_cat, W_enc, b_enc,
                                     buf_emb, sum1, sumsq1);
    k_hist<<<eb, 256, 0, stream>>>(dst, bcount);
    k_finalize<<<1, 32, 0, stream>>>(sum1, sumsq1, mean1, istd1);
    k_bscan<<<1, 1024, 0, stream>>>(bcount, boff, bcur);
    k_normAB<<<nb, 256, 0, stream>>>(buf_emb, W_msg, g_all, be_all, mean1, istd1, buf_A, buf_B);
    k_scatter<<<eb, 256, 0, stream>>>(src, dst, bcur, eidx);
    k_bucket_agg<<<NB, 256, 0, stream>>>(boff, eidx, buf_B, buf_A, b_msg, sum2, sumsq2);
    k_finalize<<<1, 32, 0, stream>>>(sum2, sumsq2, mean2, istd2);
    k_out<<<nb, 256, 0, stream>>>(buf_emb, buf_A, g_conv, be_conv, mean2, istd2,
                                  W_o1, b_o1, W_o2, b_o2, (float*)d_out);
}

// Round 7
// 391.346 us; speedup vs baseline: 1.4272x; 1.4272x over previous
//
#include <hip/hip_runtime.h>
#include <math.h>

#define N_NODES 100000
#define N_EDGES 1600000
#define HID 32
#define BN_EPS 1e-3f
#define CAP 64           // fixed slot capacity per node (Poisson(16) tail: P(deg>64) ~ 1e-20)

__device__ __forceinline__ float eluf(float x) { return x > 0.f ? x : expm1f(x); }

__device__ __forceinline__ float wave_sum64(float v) {
#pragma unroll
    for (int off = 32; off > 0; off >>= 1) v += __shfl_xor(v, off, 64);
    return v;
}

// monotonic order-preserving encode float -> uint (0 = unreachable sentinel for finite inputs)
__device__ __forceinline__ unsigned int encf(float f) {
    unsigned int u = __float_as_uint(f);
    return (u & 0x80000000u) ? ~u : (u | 0x80000000u);
}
__device__ __forceinline__ float decf(unsigned int k) {
    return __uint_as_float((k & 0x80000000u) ? (k & 0x7FFFFFFFu) : ~k);
}

// ---------------- kernel 1: node encoder + BN1 partial stats ----------------
__global__ __launch_bounds__(256) void k_encode(
    const float* __restrict__ x_cont, const int* __restrict__ x_cat,
    const float* __restrict__ datanorm,
    const float* __restrict__ W_cont, const float* __restrict__ b_cont,
    const float* __restrict__ emb_charge, const float* __restrict__ emb_pdg,
    const float* __restrict__ W_cat, const float* __restrict__ b_cat,
    const float* __restrict__ W_enc, const float* __restrict__ b_enc,
    float* __restrict__ emb_out, float* __restrict__ sum1, float* __restrict__ sumsq1)
{
    __shared__ __align__(16) float sWc[6 * 16];
    __shared__ __align__(16) float sWcat[16 * 16];
    __shared__ __align__(16) float sWenc[32 * 32];
    __shared__ __align__(16) float sbc[16];
    __shared__ __align__(16) float sbcat[16];
    __shared__ __align__(16) float sbenc[32];
    __shared__ float sdn[6], sech[3 * 8], sepd[7 * 8];
    __shared__ float ps[4][32], pq[4][32];

    int tid = threadIdx.x;
    for (int t = tid; t < 96; t += 256) sWc[t] = W_cont[t];
    for (int t = tid; t < 256; t += 256) sWcat[t] = W_cat[t];
    for (int t = tid; t < 1024; t += 256) sWenc[t] = W_enc[t];
    if (tid < 16) { sbc[tid] = b_cont[tid]; sbcat[tid] = b_cat[tid]; }
    if (tid < 32) sbenc[tid] = b_enc[tid];
    if (tid < 6)  sdn[tid] = datanorm[tid];
    if (tid < 24) sech[tid] = emb_charge[tid];
    if (tid < 56) sepd[tid] = emb_pdg[tid];
    __syncthreads();

    int n = blockIdx.x * 256 + tid;
    float e[32];
    if (n < N_NODES) {
        float xc[6];
#pragma unroll
        for (int i = 0; i < 6; i++) xc[i] = x_cont[n * 6 + i] * sdn[i];

        float cont[16];
        {
            const float4* W4 = (const float4*)sWc;
            const float4* b4 = (const float4*)sbc;
#pragma unroll
            for (int j4 = 0; j4 < 4; j4++) {
                float4 acc = b4[j4];
#pragma unroll
                for (int i = 0; i < 6; i++) {
                    float4 w = W4[i * 4 + j4];
                    acc.x += xc[i] * w.x; acc.y += xc[i] * w.y;
                    acc.z += xc[i] * w.z; acc.w += xc[i] * w.w;
                }
                cont[j4 * 4 + 0] = eluf(acc.x); cont[j4 * 4 + 1] = eluf(acc.y);
                cont[j4 * 4 + 2] = eluf(acc.z); cont[j4 * 4 + 3] = eluf(acc.w);
            }
        }

        int pdg = x_cat[n * 2 + 0], chg = x_cat[n * 2 + 1];
        int p = pdg < 0 ? -pdg : pdg;
        int pidx;
        switch (p) {
            case 1: pidx = 0; break; case 2: pidx = 1; break;
            case 11: pidx = 2; break; case 13: pidx = 3; break;
            case 22: pidx = 4; break; case 130: pidx = 5; break;
            case 211: pidx = 6; break; default: pidx = 0; break;
        }
        float cin[16];
#pragma unroll
        for (int k = 0; k < 8; k++) cin[k] = sech[(chg + 1) * 8 + k];
#pragma unroll
        for (int k = 0; k < 8; k++) cin[8 + k] = sepd[pidx * 8 + k];

        float cat[16];
        {
            const float4* W4 = (const float4*)sWcat;
            const float4* b4 = (const float4*)sbcat;
#pragma unroll
            for (int j4 = 0; j4 < 4; j4++) {
                float4 acc = b4[j4];
#pragma unroll
                for (int i = 0; i < 16; i++) {
                    float4 w = W4[i * 4 + j4];
                    acc.x += cin[i] * w.x; acc.y += cin[i] * w.y;
                    acc.z += cin[i] * w.z; acc.w += cin[i] * w.w;
                }
                cat[j4 * 4 + 0] = eluf(acc.x); cat[j4 * 4 + 1] = eluf(acc.y);
                cat[j4 * 4 + 2] = eluf(acc.z); cat[j4 * 4 + 3] = eluf(acc.w);
            }
        }

        float in32[32];
#pragma unroll
        for (int k = 0; k < 16; k++) { in32[k] = cat[k]; in32[16 + k] = cont[k]; }

        {
            const float4* W4 = (const float4*)sWenc;
            const float4* b4 = (const float4*)sbenc;
#pragma unroll
            for (int j4 = 0; j4 < 8; j4++) {
                float4 acc = b4[j4];
#pragma unroll
                for (int i = 0; i < 32; i++) {
                    float4 w = W4[i * 8 + j4];
                    acc.x += in32[i] * w.x; acc.y += in32[i] * w.y;
                    acc.z += in32[i] * w.z; acc.w += in32[i] * w.w;
                }
                e[j4 * 4 + 0] = eluf(acc.x); e[j4 * 4 + 1] = eluf(acc.y);
                e[j4 * 4 + 2] = eluf(acc.z); e[j4 * 4 + 3] = eluf(acc.w);
            }
        }
        float4* out4 = (float4*)(emb_out + (size_t)n * 32);
#pragma unroll
        for (int j4 = 0; j4 < 8; j4++)
            out4[j4] = make_float4(e[j4 * 4 + 0], e[j4 * 4 + 1], e[j4 * 4 + 2], e[j4 * 4 + 3]);
    } else {
#pragma unroll
        for (int j = 0; j < 32; j++) e[j] = 0.f;
    }

    // BN1 partial stats
    int lane = tid & 63, wid = tid >> 6;
#pragma unroll
    for (int c = 0; c < 32; c++) {
        float s = wave_sum64(e[c]);
        float q = wave_sum64(e[c] * e[c]);
        if (lane == 0) { ps[wid][c] = s; pq[wid][c] = q; }
    }
    __syncthreads();
    if (tid < 32) {
        atomicAdd(&sum1[tid], ps[0][tid] + ps[1][tid] + ps[2][tid] + ps[3][tid]);
        atomicAdd(&sumsq1[tid], pq[0][tid] + pq[1][tid] + pq[2][tid] + pq[3][tid]);
    }
}

// ---------------- kernel 2: apply BN1 (inline finalize), A = e@(W0-W1), B = e@W1 -------
__global__ __launch_bounds__(256) void k_normAB(
    float* __restrict__ emb,           // in: pre-BN, out: normalized (in place)
    const float* __restrict__ W_msg,
    const float* __restrict__ g, const float* __restrict__ be,
    const float* __restrict__ sum1, const float* __restrict__ sumsq1,
    float* __restrict__ A, float* __restrict__ B)
{
    __shared__ __align__(16) float sWA[32 * 32];
    __shared__ __align__(16) float sWB[32 * 32];
    __shared__ float sg[32], sb[32], sm[32], si[32];
    int tid = threadIdx.x;
    for (int t = tid; t < 1024; t += 256) {
        float w0 = W_msg[t];
        float w1 = W_msg[1024 + t];
        sWA[t] = w0 - w1;
        sWB[t] = w1;
    }
    if (tid < 32) {
        sg[tid] = g[tid]; sb[tid] = be[tid];
        float m = sum1[tid] / (float)N_NODES;
        float v = sumsq1[tid] / (float)N_NODES - m * m;
        sm[tid] = m;
        si[tid] = 1.0f / sqrtf(v + BN_EPS);
    }
    __syncthreads();

    int n = blockIdx.x * 256 + tid;
    if (n >= N_NODES) return;

    float e[32];
    float4* base4 = (float4*)(emb + (size_t)n * 32);
#pragma unroll
    for (int j4 = 0; j4 < 8; j4++) {
        float4 v = base4[j4];
        e[j4 * 4 + 0] = v.x; e[j4 * 4 + 1] = v.y; e[j4 * 4 + 2] = v.z; e[j4 * 4 + 3] = v.w;
    }
#pragma unroll
    for (int j = 0; j < 32; j++) e[j] = sg[j] * (e[j] - sm[j]) * si[j] + sb[j];
#pragma unroll
    for (int j4 = 0; j4 < 8; j4++)
        base4[j4] = make_float4(e[j4 * 4 + 0], e[j4 * 4 + 1], e[j4 * 4 + 2], e[j4 * 4 + 3]);

    float a[32], bb[32];
#pragma unroll
    for (int j = 0; j < 32; j++) { a[j] = 0.f; bb[j] = 0.f; }
    const float4* WA4 = (const float4*)sWA;
    const float4* WB4 = (const float4*)sWB;
#pragma unroll
    for (int i = 0; i < 32; i++) {
        float x = e[i];
#pragma unroll
        for (int j4 = 0; j4 < 8; j4++) {
            float4 wa = WA4[i * 8 + j4];
            float4 wb = WB4[i * 8 + j4];
            a[j4 * 4 + 0] += x * wa.x; a[j4 * 4 + 1] += x * wa.y;
            a[j4 * 4 + 2] += x * wa.z; a[j4 * 4 + 3] += x * wa.w;
            bb[j4 * 4 + 0] += x * wb.x; bb[j4 * 4 + 1] += x * wb.y;
            bb[j4 * 4 + 2] += x * wb.z; bb[j4 * 4 + 3] += x * wb.w;
        }
    }
    float4* A4 = (float4*)(A + (size_t)n * 32);
    float4* B4 = (float4*)(B + (size_t)n * 32);
#pragma unroll
    for (int j4 = 0; j4 < 8; j4++) {
        A4[j4] = make_float4(a[j4 * 4 + 0], a[j4 * 4 + 1], a[j4 * 4 + 2], a[j4 * 4 + 3]);
        B4[j4] = make_float4(bb[j4 * 4 + 0], bb[j4 * 4 + 1], bb[j4 * 4 + 2], bb[j4 * 4 + 3]);
    }
}

// ---------------- kernel 3: scatter src into fixed 64-slot buckets (no hist/scan) ------
__global__ __launch_bounds__(256) void k_scatter(
    const int* __restrict__ src, const int* __restrict__ dst,
    int* __restrict__ cnt, int* __restrict__ eidx,
    const float* __restrict__ B, unsigned int* __restrict__ maxB)
{
    int e = blockIdx.x * 256 + threadIdx.x;
    if (e >= N_EDGES) return;
    int d = dst[e];
    int pos = atomicAdd(&cnt[d], 1);
    if (pos < CAP) {
        eidx[(size_t)d * CAP + pos] = src[e];
    } else {
        // statistically unreachable overflow path: direct global max
        int s = src[e];
        unsigned int* row = maxB + (size_t)d * 32;
        for (int c = 0; c < 32; c++) atomicMax(row + c, encf(B[(size_t)s * 32 + c]));
    }
}

// ---------------- kernel 4: bucket gather-max + agg + BN2 partial stats ----------------
// 32 nodes per 256-thread block; 8 lanes per node, 4 channels per lane.
__global__ __launch_bounds__(256) void k_gather_agg(
    const int* __restrict__ cnt, const int* __restrict__ eidx,
    const unsigned int* __restrict__ maxB,
    const float* __restrict__ B,
    float* __restrict__ A,             // in: A, out: agg (in place)
    const float* __restrict__ b_msg,
    float* __restrict__ sum2, float* __restrict__ sumsq2)
{
    __shared__ float sb[32];
    __shared__ float ps[4][32], pq[4][32];
    int tid = threadIdx.x;
    if (tid < 32) sb[tid] = b_msg[tid];
    __syncthreads();

    int grp = tid >> 3;                 // node slot 0..31
    int sub = tid & 7;                  // channels 4*sub..4*sub+3
    int n = blockIdx.x * 32 + grp;      // grid is exactly N/32 = 3125 blocks
    int deg = cnt[n];
    int end = deg < CAP ? deg : CAP;
    const int* slots = eidx + (size_t)n * CAP;

    float4 mx = make_float4(-INFINITY, -INFINITY, -INFINITY, -INFINITY);
    int k = 0;
    for (; k + 3 < end; k += 4) {
        int s0 = slots[k], s1 = slots[k + 1], s2 = slots[k + 2], s3 = slots[k + 3];
        float4 v0 = *(const float4*)(B + (size_t)s0 * 32 + sub * 4);
        float4 v1 = *(const float4*)(B + (size_t)s1 * 32 + sub * 4);
        float4 v2 = *(const float4*)(B + (size_t)s2 * 32 + sub * 4);
        float4 v3 = *(const float4*)(B + (size_t)s3 * 32 + sub * 4);
        mx.x = fmaxf(fmaxf(mx.x, fmaxf(v0.x, v1.x)), fmaxf(v2.x, v3.x));
        mx.y = fmaxf(fmaxf(mx.y, fmaxf(v0.y, v1.y)), fmaxf(v2.y, v3.y));
        mx.z = fmaxf(fmaxf(mx.z, fmaxf(v0.z, v1.z)), fmaxf(v2.z, v3.z));
        mx.w = fmaxf(fmaxf(mx.w, fmaxf(v0.w, v1.w)), fmaxf(v2.w, v3.w));
    }
    for (; k < end; k++) {
        int s0 = slots[k];
        float4 v0 = *(const float4*)(B + (size_t)s0 * 32 + sub * 4);
        mx.x = fmaxf(mx.x, v0.x); mx.y = fmaxf(mx.y, v0.y);
        mx.z = fmaxf(mx.z, v0.z); mx.w = fmaxf(mx.w, v0.w);
    }
    if (deg > CAP) {  // merge overflow partial max (never expected in practice)
        const unsigned int* row = maxB + (size_t)n * 32 + sub * 4;
        unsigned int k0 = row[0], k1 = row[1], k2 = row[2], k3 = row[3];
        if (k0) mx.x = fmaxf(mx.x, decf(k0));
        if (k1) mx.y = fmaxf(mx.y, decf(k1));
        if (k2) mx.z = fmaxf(mx.z, decf(k2));
        if (k3) mx.w = fmaxf(mx.w, decf(k3));
    }

    float4* arow = (float4*)(A + (size_t)n * 32 + sub * 4);
    float4 a = *arow;
    float4 agg;
    if (deg > 0) {
        agg.x = a.x + sb[sub * 4 + 0] + mx.x;
        agg.y = a.y + sb[sub * 4 + 1] + mx.y;
        agg.z = a.z + sb[sub * 4 + 2] + mx.z;
        agg.w = a.w + sb[sub * 4 + 3] + mx.w;
    } else {
        agg = make_float4(0.f, 0.f, 0.f, 0.f);
    }
    *arow = agg;

    // BN2 partial stats: sum over the 8 nodes in each wave per channel group.
    float s0 = agg.x, s1 = agg.y, s2 = agg.z, s3 = agg.w;
    float q0 = agg.x * agg.x, q1 = agg.y * agg.y, q2 = agg.z * agg.z, q3 = agg.w * agg.w;
#pragma unroll
    for (int o = 8; o < 64; o <<= 1) {
        s0 += __shfl_xor(s0, o, 64); s1 += __shfl_xor(s1, o, 64);
        s2 += __shfl_xor(s2, o, 64); s3 += __shfl_xor(s3, o, 64);
        q0 += __shfl_xor(q0, o, 64); q1 += __shfl_xor(q1, o, 64);
        q2 += __shfl_xor(q2, o, 64); q3 += __shfl_xor(q3, o, 64);
    }
    int lane = tid & 63, wid = tid >> 6;
    if (lane < 8) {
        ps[wid][lane * 4 + 0] = s0; ps[wid][lane * 4 + 1] = s1;
        ps[wid][lane * 4 + 2] = s2; ps[wid][lane * 4 + 3] = s3;
        pq[wid][lane * 4 + 0] = q0; pq[wid][lane * 4 + 1] = q1;
        pq[wid][lane * 4 + 2] = q2; pq[wid][lane * 4 + 3] = q3;
    }
    __syncthreads();
    if (tid < 32) {
        atomicAdd(&sum2[tid], ps[0][tid] + ps[1][tid] + ps[2][tid] + ps[3][tid]);
        atomicAdd(&sumsq2[tid], pq[0][tid] + pq[1][tid] + pq[2][tid] + pq[3][tid]);
    }
}

// ---------------- kernel 5: residual + BN2 (inline finalize) + output head -------------
__global__ __launch_bounds__(256) void k_out(
    const float* __restrict__ emb, const float* __restrict__ agg,
    const float* __restrict__ g, const float* __restrict__ be,
    const float* __restrict__ sum2, const float* __restrict__ sumsq2,
    const float* __restrict__ W_o1, const float* __restrict__ b_o1,
    const float* __restrict__ W_o2, const float* __restrict__ b_o2,
    float* __restrict__ out)
{
    __shared__ __align__(16) float sW1[32 * 16];
    __shared__ __align__(16) float sb1[16];
    __shared__ float sW2[16], sg[32], sbe[32], sm[32], si[32];
    __shared__ float sb2;
    int tid = threadIdx.x;
    for (int t = tid; t < 512; t += 256) sW1[t] = W_o1[t];
    if (tid < 16) { sW2[tid] = W_o2[tid]; sb1[tid] = b_o1[tid]; }
    if (tid < 32) {
        sg[tid] = g[tid]; sbe[tid] = be[tid];
        float m = sum2[tid] / (float)N_NODES;
        float v = sumsq2[tid] / (float)N_NODES - m * m;
        sm[tid] = m;
        si[tid] = 1.0f / sqrtf(v + BN_EPS);
    }
    if (tid == 0) sb2 = b_o2[0];
    __syncthreads();

    int n = blockIdx.x * 256 + tid;
    if (n >= N_NODES) return;

    float h[32];
    const float4* e4 = (const float4*)(emb + (size_t)n * 32);
    const float4* a4 = (const float4*)(agg + (size_t)n * 32);
#pragma unroll
    for (int j4 = 0; j4 < 8; j4++) {
        float4 ev = e4[j4];
        float4 av = a4[j4];
        h[j4 * 4 + 0] = ev.x + sg[j4 * 4 + 0] * (av.x - sm[j4 * 4 + 0]) * si[j4 * 4 + 0] + sbe[j4 * 4 + 0];
        h[j4 * 4 + 1] = ev.y + sg[j4 * 4 + 1] * (av.y - sm[j4 * 4 + 1]) * si[j4 * 4 + 1] + sbe[j4 * 4 + 1];
        h[j4 * 4 + 2] = ev.z + sg[j4 * 4 + 2] * (av.z - sm[j4 * 4 + 2]) * si[j4 * 4 + 2] + sbe[j4 * 4 + 2];
        h[j4 * 4 + 3] = ev.w + sg[j4 * 4 + 3] * (av.w - sm[j4 * 4 + 3]) * si[j4 * 4 + 3] + sbe[j4 * 4 + 3];
    }

    float o1[16];
    const float4* W14 = (const float4*)sW1;
    const float4* b14 = (const float4*)sb1;
#pragma unroll
    for (int j4 = 0; j4 < 4; j4++) {
        float4 acc = b14[j4];
#pragma unroll
        for (int i = 0; i < 32; i++) {
            float4 w = W14[i * 4 + j4];
            acc.x += h[i] * w.x; acc.y += h[i] * w.y;
            acc.z += h[i] * w.z; acc.w += h[i] * w.w;
        }
        o1[j4 * 4 + 0] = eluf(acc.x); o1[j4 * 4 + 1] = eluf(acc.y);
        o1[j4 * 4 + 2] = eluf(acc.z); o1[j4 * 4 + 3] = eluf(acc.w);
    }
    float o = sb2;
#pragma unroll
    for (int k = 0; k < 16; k++) o += o1[k] * sW2[k];
    out[n] = o;
}

extern "C" void kernel_launch(void* const* d_in, const int* in_sizes, int n_in,
                              void* d_out, int out_size, void* d_ws, size_t ws_size,
                              hipStream_t stream)
{
    const float* x_cont     = (const float*)d_in[0];
    const int*   x_cat      = (const int*)d_in[1];
    const int*   edge_index = (const int*)d_in[2];
    // d_in[3] = batch (unused by reference)
    const float* datanorm   = (const float*)d_in[4];
    const float* W_cont     = (const float*)d_in[5];
    const float* b_cont     = (const float*)d_in[6];
    const float* emb_charge = (const float*)d_in[7];
    const float* emb_pdg    = (const float*)d_in[8];
    const float* W_cat      = (const float*)d_in[9];
    const float* b_cat      = (const float*)d_in[10];
    const float* W_enc      = (const float*)d_in[11];
    const float* b_enc      = (const float*)d_in[12];
    const float* g_all      = (const float*)d_in[13];
    const float* be_all     = (const float*)d_in[14];
    const float* W_msg      = (const float*)d_in[15];
    const float* b_msg      = (const float*)d_in[16];
    const float* g_conv     = (const float*)d_in[17];
    const float* be_conv    = (const float*)d_in[18];
    const float* W_o1       = (const float*)d_in[19];
    const float* b_o1       = (const float*)d_in[20];
    const float* W_o2       = (const float*)d_in[21];
    const float* b_o2       = (const float*)d_in[22];

    const size_t NH = (size_t)N_NODES * 32;
    float* buf_emb = (float*)d_ws;                  // NH floats
    float* buf_A   = buf_emb + NH;                  // NH floats
    float* buf_B   = buf_A + NH;                    // NH floats
    float* stats   = buf_B + NH;                    // 256 floats
    int*   cnt     = (int*)(stats + 256);           // N
    unsigned int* maxB = (unsigned int*)(cnt + N_NODES);  // N*32
    int*   eidx    = (int*)(maxB + NH);             // N*CAP

    float* sum1 = stats,       *sumsq1 = stats + 32;
    float* sum2 = stats + 128, *sumsq2 = stats + 160;

    hipMemsetAsync(stats, 0, 256 * sizeof(float), stream);
    hipMemsetAsync(cnt, 0, N_NODES * sizeof(int), stream);
    hipMemsetAsync(maxB, 0, NH * sizeof(unsigned int), stream);

    const int* src = edge_index;
    const int* dst = edge_index + N_EDGES;

    int nb = (N_NODES + 255) / 256;
    int eb = N_EDGES / 256;  // 6250 exact

    k_encode<<<nb, 256, 0, stream>>>(x_cont, x_cat, datanorm, W_cont, b_cont,
                                     emb_charge, emb_pdg, W_cat, b_cat, W_enc, b_enc,
                                     buf_emb, sum1, sumsq1);
    k_normAB<<<nb, 256, 0, stream>>>(buf_emb, W_msg, g_all, be_all, sum1, sumsq1, buf_A, buf_B);
    k_scatter<<<eb, 256, 0, stream>>>(src, dst, cnt, eidx, buf_B, maxB);
    k_gather_agg<<<N_NODES / 32, 256, 0, stream>>>(cnt, eidx, maxB, buf_B, buf_A, b_msg, sum2, sumsq2);
    k_out<<<nb, 256, 0, stream>>>(buf_emb, buf_A, g_conv, be_conv, sum2, sumsq2,
                                  W_o1, b_o1, W_o2, b_o2, (float*)d_out);
}

// Round 9
// 241.395 us; speedup vs baseline: 2.3137x; 1.6212x over previous
//
#include <hip/hip_runtime.h>
#include <math.h>

#define N_NODES 100000
#define N_EDGES 1600000
#define HID 32
#define BN_EPS 1e-3f
#define NBUCK 782        // buckets of 128 nodes: ceil(100000/128)
#define CAPB 2432        // slots per bucket (mean 2046, sigma~45 -> 8.5 sigma headroom)
#define BIN_E 4096       // edges per binning block
#define OVF_MAX 65536

__device__ __forceinline__ float eluf(float x) { return x > 0.f ? x : expm1f(x); }

__device__ __forceinline__ float wave_sum64(float v) {
#pragma unroll
    for (int off = 32; off > 0; off >>= 1) v += __shfl_xor(v, off, 64);
    return v;
}

// monotonic order-preserving encode float -> uint (0 = unreachable sentinel for finite inputs)
__device__ __forceinline__ unsigned int encf(float f) {
    unsigned int u = __float_as_uint(f);
    return (u & 0x80000000u) ? ~u : (u | 0x80000000u);
}
__device__ __forceinline__ float decf(unsigned int k) {
    return __uint_as_float((k & 0x80000000u) ? (k & 0x7FFFFFFFu) : ~k);
}

// ---------------- kernel 1: node encoder + BN1 partial stats ----------------
__global__ __launch_bounds__(256) void k_encode(
    const float* __restrict__ x_cont, const int* __restrict__ x_cat,
    const float* __restrict__ datanorm,
    const float* __restrict__ W_cont, const float* __restrict__ b_cont,
    const float* __restrict__ emb_charge, const float* __restrict__ emb_pdg,
    const float* __restrict__ W_cat, const float* __restrict__ b_cat,
    const float* __restrict__ W_enc, const float* __restrict__ b_enc,
    float* __restrict__ emb_out, float* __restrict__ sum1, float* __restrict__ sumsq1)
{
    __shared__ __align__(16) float sWc[6 * 16];
    __shared__ __align__(16) float sWcat[16 * 16];
    __shared__ __align__(16) float sWenc[32 * 32];
    __shared__ __align__(16) float sbc[16];
    __shared__ __align__(16) float sbcat[16];
    __shared__ __align__(16) float sbenc[32];
    __shared__ float sdn[6], sech[3 * 8], sepd[7 * 8];
    __shared__ float ps[4][32], pq[4][32];

    int tid = threadIdx.x;
    for (int t = tid; t < 96; t += 256) sWc[t] = W_cont[t];
    for (int t = tid; t < 256; t += 256) sWcat[t] = W_cat[t];
    for (int t = tid; t < 1024; t += 256) sWenc[t] = W_enc[t];
    if (tid < 16) { sbc[tid] = b_cont[tid]; sbcat[tid] = b_cat[tid]; }
    if (tid < 32) sbenc[tid] = b_enc[tid];
    if (tid < 6)  sdn[tid] = datanorm[tid];
    if (tid < 24) sech[tid] = emb_charge[tid];
    if (tid < 56) sepd[tid] = emb_pdg[tid];
    __syncthreads();

    int n = blockIdx.x * 256 + tid;
    float e[32];
    if (n < N_NODES) {
        float xc[6];
#pragma unroll
        for (int i = 0; i < 6; i++) xc[i] = x_cont[n * 6 + i] * sdn[i];

        float cont[16];
        {
            const float4* W4 = (const float4*)sWc;
            const float4* b4 = (const float4*)sbc;
#pragma unroll
            for (int j4 = 0; j4 < 4; j4++) {
                float4 acc = b4[j4];
#pragma unroll
                for (int i = 0; i < 6; i++) {
                    float4 w = W4[i * 4 + j4];
                    acc.x += xc[i] * w.x; acc.y += xc[i] * w.y;
                    acc.z += xc[i] * w.z; acc.w += xc[i] * w.w;
                }
                cont[j4 * 4 + 0] = eluf(acc.x); cont[j4 * 4 + 1] = eluf(acc.y);
                cont[j4 * 4 + 2] = eluf(acc.z); cont[j4 * 4 + 3] = eluf(acc.w);
            }
        }

        int pdg = x_cat[n * 2 + 0], chg = x_cat[n * 2 + 1];
        int p = pdg < 0 ? -pdg : pdg;
        int pidx;
        switch (p) {
            case 1: pidx = 0; break; case 2: pidx = 1; break;
            case 11: pidx = 2; break; case 13: pidx = 3; break;
            case 22: pidx = 4; break; case 130: pidx = 5; break;
            case 211: pidx = 6; break; default: pidx = 0; break;
        }
        float cin[16];
#pragma unroll
        for (int k = 0; k < 8; k++) cin[k] = sech[(chg + 1) * 8 + k];
#pragma unroll
        for (int k = 0; k < 8; k++) cin[8 + k] = sepd[pidx * 8 + k];

        float cat[16];
        {
            const float4* W4 = (const float4*)sWcat;
            const float4* b4 = (const float4*)sbcat;
#pragma unroll
            for (int j4 = 0; j4 < 4; j4++) {
                float4 acc = b4[j4];
#pragma unroll
                for (int i = 0; i < 16; i++) {
                    float4 w = W4[i * 4 + j4];
                    acc.x += cin[i] * w.x; acc.y += cin[i] * w.y;
                    acc.z += cin[i] * w.z; acc.w += cin[i] * w.w;
                }
                cat[j4 * 4 + 0] = eluf(acc.x); cat[j4 * 4 + 1] = eluf(acc.y);
                cat[j4 * 4 + 2] = eluf(acc.z); cat[j4 * 4 + 3] = eluf(acc.w);
            }
        }

        float in32[32];
#pragma unroll
        for (int k = 0; k < 16; k++) { in32[k] = cat[k]; in32[16 + k] = cont[k]; }

        {
            const float4* W4 = (const float4*)sWenc;
            const float4* b4 = (const float4*)sbenc;
#pragma unroll
            for (int j4 = 0; j4 < 8; j4++) {
                float4 acc = b4[j4];
#pragma unroll
                for (int i = 0; i < 32; i++) {
                    float4 w = W4[i * 8 + j4];
                    acc.x += in32[i] * w.x; acc.y += in32[i] * w.y;
                    acc.z += in32[i] * w.z; acc.w += in32[i] * w.w;
                }
                e[j4 * 4 + 0] = eluf(acc.x); e[j4 * 4 + 1] = eluf(acc.y);
                e[j4 * 4 + 2] = eluf(acc.z); e[j4 * 4 + 3] = eluf(acc.w);
            }
        }
        float4* out4 = (float4*)(emb_out + (size_t)n * 32);
#pragma unroll
        for (int j4 = 0; j4 < 8; j4++)
            out4[j4] = make_float4(e[j4 * 4 + 0], e[j4 * 4 + 1], e[j4 * 4 + 2], e[j4 * 4 + 3]);
    } else {
#pragma unroll
        for (int j = 0; j < 32; j++) e[j] = 0.f;
    }

    // BN1 partial stats
    int lane = tid & 63, wid = tid >> 6;
#pragma unroll
    for (int c = 0; c < 32; c++) {
        float s = wave_sum64(e[c]);
        float q = wave_sum64(e[c] * e[c]);
        if (lane == 0) { ps[wid][c] = s; pq[wid][c] = q; }
    }
    __syncthreads();
    if (tid < 32) {
        atomicAdd(&sum1[tid], ps[0][tid] + ps[1][tid] + ps[2][tid] + ps[3][tid]);
        atomicAdd(&sumsq1[tid], pq[0][tid] + pq[1][tid] + pq[2][tid] + pq[3][tid]);
    }
}

// ---------------- kernel 2: apply BN1 (inline finalize), A = e@(W0-W1), B = e@W1 -------
__global__ __launch_bounds__(256) void k_normAB(
    float* __restrict__ emb,
    const float* __restrict__ W_msg,
    const float* __restrict__ g, const float* __restrict__ be,
    const float* __restrict__ sum1, const float* __restrict__ sumsq1,
    float* __restrict__ A, float* __restrict__ B)
{
    __shared__ __align__(16) float sWA[32 * 32];
    __shared__ __align__(16) float sWB[32 * 32];
    __shared__ float sg[32], sb[32], sm[32], si[32];
    int tid = threadIdx.x;
    for (int t = tid; t < 1024; t += 256) {
        float w0 = W_msg[t];
        float w1 = W_msg[1024 + t];
        sWA[t] = w0 - w1;
        sWB[t] = w1;
    }
    if (tid < 32) {
        sg[tid] = g[tid]; sb[tid] = be[tid];
        float m = sum1[tid] / (float)N_NODES;
        float v = sumsq1[tid] / (float)N_NODES - m * m;
        sm[tid] = m;
        si[tid] = 1.0f / sqrtf(v + BN_EPS);
    }
    __syncthreads();

    int n = blockIdx.x * 256 + tid;
    if (n >= N_NODES) return;

    float e[32];
    float4* base4 = (float4*)(emb + (size_t)n * 32);
#pragma unroll
    for (int j4 = 0; j4 < 8; j4++) {
        float4 v = base4[j4];
        e[j4 * 4 + 0] = v.x; e[j4 * 4 + 1] = v.y; e[j4 * 4 + 2] = v.z; e[j4 * 4 + 3] = v.w;
    }
#pragma unroll
    for (int j = 0; j < 32; j++) e[j] = sg[j] * (e[j] - sm[j]) * si[j] + sb[j];
#pragma unroll
    for (int j4 = 0; j4 < 8; j4++)
        base4[j4] = make_float4(e[j4 * 4 + 0], e[j4 * 4 + 1], e[j4 * 4 + 2], e[j4 * 4 + 3]);

    float a[32], bb[32];
#pragma unroll
    for (int j = 0; j < 32; j++) { a[j] = 0.f; bb[j] = 0.f; }
    const float4* WA4 = (const float4*)sWA;
    const float4* WB4 = (const float4*)sWB;
#pragma unroll
    for (int i = 0; i < 32; i++) {
        float x = e[i];
#pragma unroll
        for (int j4 = 0; j4 < 8; j4++) {
            float4 wa = WA4[i * 8 + j4];
            float4 wb = WB4[i * 8 + j4];
            a[j4 * 4 + 0] += x * wa.x; a[j4 * 4 + 1] += x * wa.y;
            a[j4 * 4 + 2] += x * wa.z; a[j4 * 4 + 3] += x * wa.w;
            bb[j4 * 4 + 0] += x * wb.x; bb[j4 * 4 + 1] += x * wb.y;
            bb[j4 * 4 + 2] += x * wb.z; bb[j4 * 4 + 3] += x * wb.w;
        }
    }
    float4* A4 = (float4*)(A + (size_t)n * 32);
    float4* B4 = (float4*)(B + (size_t)n * 32);
#pragma unroll
    for (int j4 = 0; j4 < 8; j4++) {
        A4[j4] = make_float4(a[j4 * 4 + 0], a[j4 * 4 + 1], a[j4 * 4 + 2], a[j4 * 4 + 3]);
        B4[j4] = make_float4(bb[j4 * 4 + 0], bb[j4 * 4 + 1], bb[j4 * 4 + 2], bb[j4 * 4 + 3]);
    }
}

// ---------------- kernel 3: LDS-staged multisplit binning of edges by dst bucket -------
// Packed entry: (dst & 127) << 17 | src   (src < 131072)
__global__ __launch_bounds__(1024) void k_bin(
    const int* __restrict__ src, const int* __restrict__ dst,
    int* __restrict__ cnt, unsigned int* __restrict__ eidx,
    unsigned long long* __restrict__ ovf, int* __restrict__ ovfn)
{
    __shared__ unsigned int lcnt[NBUCK];
    __shared__ unsigned int lbase[NBUCK];
    __shared__ unsigned int gbase[NBUCK];
    __shared__ unsigned int sc[1024];
    __shared__ unsigned int sg[BIN_E];
    __shared__ unsigned int sd[BIN_E];
    __shared__ unsigned int s_total;

    int tid = threadIdx.x;
    for (int i = tid; i < NBUCK; i += 1024) lcnt[i] = 0;
    __syncthreads();

    int e0 = blockIdx.x * BIN_E;
    int b_[4]; unsigned int p_[4], r_[4]; bool v_[4];
#pragma unroll
    for (int i = 0; i < 4; i++) {
        int e = e0 + i * 1024 + tid;
        v_[i] = (e < N_EDGES);
        b_[i] = 0; p_[i] = 0; r_[i] = 0;
        if (v_[i]) {
            int d = dst[e], s = src[e];
            b_[i] = d >> 7;
            p_[i] = ((unsigned int)(d & 127) << 17) | (unsigned int)s;
            r_[i] = atomicAdd(&lcnt[b_[i]], 1u);
        }
    }
    __syncthreads();

    // exclusive scan of lcnt over NBUCK (Hillis-Steele, 1024 wide)
    sc[tid] = (tid < NBUCK) ? lcnt[tid] : 0;
    __syncthreads();
    for (int o = 1; o < 1024; o <<= 1) {
        unsigned int u = (tid >= o) ? sc[tid - o] : 0;
        __syncthreads();
        sc[tid] += u;
        __syncthreads();
    }
    if (tid < NBUCK) lbase[tid] = sc[tid] - lcnt[tid];
    if (tid == 0) s_total = sc[1023];
    if (tid < NBUCK && lcnt[tid] > 0)
        gbase[tid] = (unsigned int)atomicAdd(&cnt[tid], (int)lcnt[tid]);
    __syncthreads();

    // group into LDS + compute global destinations
#pragma unroll
    for (int i = 0; i < 4; i++) {
        if (v_[i]) {
            unsigned int slot = lbase[b_[i]] + r_[i];
            sg[slot] = p_[i];
            unsigned int gpos = gbase[b_[i]] + r_[i];
            if (gpos < CAPB) {
                sd[slot] = (unsigned int)b_[i] * CAPB + gpos;
            } else {
                sd[slot] = 0xFFFFFFFFu;   // statistically unreachable overflow
                int oi = atomicAdd(ovfn, 1);
                if (oi < OVF_MAX) ovf[oi] = ((unsigned long long)b_[i] << 32) | p_[i];
            }
        }
    }
    __syncthreads();

    // coalesced-run writeout
    unsigned int tot = s_total;
    for (unsigned int t = tid; t < tot; t += 1024) {
        unsigned int d = sd[t];
        if (d != 0xFFFFFFFFu) eidx[d] = sg[t];
    }
}

// ---------------- kernel 4: per-bucket LDS-atomic segment max + agg + BN2 stats --------
// One block per bucket (128 nodes). 64 edge slots x 8 channel lanes = 512 threads.
__global__ __launch_bounds__(512) void k_fine(
    const int* __restrict__ cnt, const unsigned int* __restrict__ eidx,
    const unsigned long long* __restrict__ ovf, const int* __restrict__ ovfn,
    const float* __restrict__ B,
    float* __restrict__ A,             // in: A, out: agg (in place)
    const float* __restrict__ b_msg,
    float* __restrict__ sum2, float* __restrict__ sumsq2)
{
    __shared__ unsigned int smax[128 * 33];  // [node][ch], stride 33 breaks bank aliasing
    __shared__ float sb[32];
    __shared__ float ps[8][32], pq[8][32];
    int tid = threadIdx.x;
    if (tid < 32) sb[tid] = b_msg[tid];
    for (int i = tid; i < 128 * 33; i += 512) smax[i] = 0u;
    __syncthreads();

    int b = blockIdx.x;
    int ne = cnt[b]; if (ne > CAPB) ne = CAPB;
    const unsigned int* eb = eidx + (size_t)b * CAPB;
    int slot = tid >> 3, sub = tid & 7;

    for (int k = slot; k < ne; k += 64) {
        unsigned int p = eb[k];
        int dl = (int)(p >> 17);
        int s  = (int)(p & 0x1FFFFu);
        float4 bv = *(const float4*)(B + (size_t)s * 32 + sub * 4);
        unsigned int* row = &smax[dl * 33 + sub * 4];
        atomicMax(row + 0, encf(bv.x));
        atomicMax(row + 1, encf(bv.y));
        atomicMax(row + 2, encf(bv.z));
        atomicMax(row + 3, encf(bv.w));
    }
    int on = *ovfn;
    for (int k = slot; k < on; k += 64) {           // normally on == 0
        unsigned long long oe = ovf[k];
        if ((int)(oe >> 32) == b) {
            unsigned int p = (unsigned int)oe;
            int dl = (int)(p >> 17);
            int s  = (int)(p & 0x1FFFFu);
            float4 bv = *(const float4*)(B + (size_t)s * 32 + sub * 4);
            unsigned int* row = &smax[dl * 33 + sub * 4];
            atomicMax(row + 0, encf(bv.x));
            atomicMax(row + 1, encf(bv.y));
            atomicMax(row + 2, encf(bv.z));
            atomicMax(row + 3, encf(bv.w));
        }
    }
    __syncthreads();

    // finalize 128 nodes: agg = A + b_msg + max (or 0); accumulate BN2 stats
    float s0 = 0.f, s1 = 0.f, s2 = 0.f, s3 = 0.f;
    float q0 = 0.f, q1 = 0.f, q2 = 0.f, q3 = 0.f;
#pragma unroll
    for (int i = 0; i < 2; i++) {
        int node = slot + i * 64;
        int n = b * 128 + node;
        if (n < N_NODES) {
            unsigned int k0 = smax[node * 33 + sub * 4 + 0];
            unsigned int k1 = smax[node * 33 + sub * 4 + 1];
            unsigned int k2 = smax[node * 33 + sub * 4 + 2];
            unsigned int k3 = smax[node * 33 + sub * 4 + 3];
            float4* arow = (float4*)(A + (size_t)n * 32 + sub * 4);
            float4 a = *arow;
            float4 agg;
            agg.x = k0 ? (decf(k0) + a.x + sb[sub * 4 + 0]) : 0.f;
            agg.y = k1 ? (decf(k1) + a.y + sb[sub * 4 + 1]) : 0.f;
            agg.z = k2 ? (decf(k2) + a.z + sb[sub * 4 + 2]) : 0.f;
            agg.w = k3 ? (decf(k3) + a.w + sb[sub * 4 + 3]) : 0.f;
            *arow = agg;
            s0 += agg.x; s1 += agg.y; s2 += agg.z; s3 += agg.w;
            q0 += agg.x * agg.x; q1 += agg.y * agg.y;
            q2 += agg.z * agg.z; q3 += agg.w * agg.w;
        }
    }
#pragma unroll
    for (int o = 8; o < 64; o <<= 1) {
        s0 += __shfl_xor(s0, o, 64); s1 += __shfl_xor(s1, o, 64);
        s2 += __shfl_xor(s2, o, 64); s3 += __shfl_xor(s3, o, 64);
        q0 += __shfl_xor(q0, o, 64); q1 += __shfl_xor(q1, o, 64);
        q2 += __shfl_xor(q2, o, 64); q3 += __shfl_xor(q3, o, 64);
    }
    int lane = tid & 63, wid = tid >> 6;
    if (lane < 8) {
        ps[wid][lane * 4 + 0] = s0; ps[wid][lane * 4 + 1] = s1;
        ps[wid][lane * 4 + 2] = s2; ps[wid][lane * 4 + 3] = s3;
        pq[wid][lane * 4 + 0] = q0; pq[wid][lane * 4 + 1] = q1;
        pq[wid][lane * 4 + 2] = q2; pq[wid][lane * 4 + 3] = q3;
    }
    __syncthreads();
    if (tid < 32) {
        float fs = 0.f, fq = 0.f;
#pragma unroll
        for (int w = 0; w < 8; w++) { fs += ps[w][tid]; fq += pq[w][tid]; }
        atomicAdd(&sum2[tid], fs);
        atomicAdd(&sumsq2[tid], fq);
    }
}

// ---------------- kernel 5: residual + BN2 (inline finalize) + output head -------------
__global__ __launch_bounds__(256) void k_out(
    const float* __restrict__ emb, const float* __restrict__ agg,
    const float* __restrict__ g, const float* __restrict__ be,
    const float* __restrict__ sum2, const float* __restrict__ sumsq2,
    const float* __restrict__ W_o1, const float* __restrict__ b_o1,
    const float* __restrict__ W_o2, const float* __restrict__ b_o2,
    float* __restrict__ out)
{
    __shared__ __align__(16) float sW1[32 * 16];
    __shared__ __align__(16) float sb1[16];
    __shared__ float sW2[16], sg[32], sbe[32], sm[32], si[32];
    __shared__ float sb2;
    int tid = threadIdx.x;
    for (int t = tid; t < 512; t += 256) sW1[t] = W_o1[t];
    if (tid < 16) { sW2[tid] = W_o2[tid]; sb1[tid] = b_o1[tid]; }
    if (tid < 32) {
        sg[tid] = g[tid]; sbe[tid] = be[tid];
        float m = sum2[tid] / (float)N_NODES;
        float v = sumsq2[tid] / (float)N_NODES - m * m;
        sm[tid] = m;
        si[tid] = 1.0f / sqrtf(v + BN_EPS);
    }
    if (tid == 0) sb2 = b_o2[0];
    __syncthreads();

    int n = blockIdx.x * 256 + tid;
    if (n >= N_NODES) return;

    float h[32];
    const float4* e4 = (const float4*)(emb + (size_t)n * 32);
    const float4* a4 = (const float4*)(agg + (size_t)n * 32);
#pragma unroll
    for (int j4 = 0; j4 < 8; j4++) {
        float4 ev = e4[j4];
        float4 av = a4[j4];
        h[j4 * 4 + 0] = ev.x + sg[j4 * 4 + 0] * (av.x - sm[j4 * 4 + 0]) * si[j4 * 4 + 0] + sbe[j4 * 4 + 0];
        h[j4 * 4 + 1] = ev.y + sg[j4 * 4 + 1] * (av.y - sm[j4 * 4 + 1]) * si[j4 * 4 + 1] + sbe[j4 * 4 + 1];
        h[j4 * 4 + 2] = ev.z + sg[j4 * 4 + 2] * (av.z - sm[j4 * 4 + 2]) * si[j4 * 4 + 2] + sbe[j4 * 4 + 2];
        h[j4 * 4 + 3] = ev.w + sg[j4 * 4 + 3] * (av.w - sm[j4 * 4 + 3]) * si[j4 * 4 + 3] + sbe[j4 * 4 + 3];
    }

    float o1[16];
    const float4* W14 = (const float4*)sW1;
    const float4* b14 = (const float4*)sb1;
#pragma unroll
    for (int j4 = 0; j4 < 4; j4++) {
        float4 acc = b14[j4];
#pragma unroll
        for (int i = 0; i < 32; i++) {
            float4 w = W14[i * 4 + j4];
            acc.x += h[i] * w.x; acc.y += h[i] * w.y;
            acc.z += h[i] * w.z; acc.w += h[i] * w.w;
        }
        o1[j4 * 4 + 0] = eluf(acc.x); o1[j4 * 4 + 1] = eluf(acc.y);
        o1[j4 * 4 + 2] = eluf(acc.z); o1[j4 * 4 + 3] = eluf(acc.w);
    }
    float o = sb2;
#pragma unroll
    for (int k = 0; k < 16; k++) o += o1[k] * sW2[k];
    out[n] = o;
}

extern "C" void kernel_launch(void* const* d_in, const int* in_sizes, int n_in,
                              void* d_out, int out_size, void* d_ws, size_t ws_size,
                              hipStream_t stream)
{
    const float* x_cont     = (const float*)d_in[0];
    const int*   x_cat      = (const int*)d_in[1];
    const int*   edge_index = (const int*)d_in[2];
    // d_in[3] = batch (unused by reference)
    const float* datanorm   = (const float*)d_in[4];
    const float* W_cont     = (const float*)d_in[5];
    const float* b_cont     = (const float*)d_in[6];
    const float* emb_charge = (const float*)d_in[7];
    const float* emb_pdg    = (const float*)d_in[8];
    const float* W_cat      = (const float*)d_in[9];
    const float* b_cat      = (const float*)d_in[10];
    const float* W_enc      = (const float*)d_in[11];
    const float* b_enc      = (const float*)d_in[12];
    const float* g_all      = (const float*)d_in[13];
    const float* be_all     = (const float*)d_in[14];
    const float* W_msg      = (const float*)d_in[15];
    const float* b_msg      = (const float*)d_in[16];
    const float* g_conv     = (const float*)d_in[17];
    const float* be_conv    = (const float*)d_in[18];
    const float* W_o1       = (const float*)d_in[19];
    const float* b_o1       = (const float*)d_in[20];
    const float* W_o2       = (const float*)d_in[21];
    const float* b_o2       = (const float*)d_in[22];

    const size_t NH = (size_t)N_NODES * 32;
    float* buf_emb = (float*)d_ws;                          // NH floats
    float* buf_A   = buf_emb + NH;                          // NH floats
    float* buf_B   = buf_A + NH;                            // NH floats
    unsigned long long* ovf = (unsigned long long*)(buf_B + NH);  // OVF_MAX (8B aligned)
    float* stats   = (float*)(ovf + OVF_MAX);               // 256 floats
    int*   cnt     = (int*)(stats + 256);                   // NBUCK
    int*   ovfn    = cnt + NBUCK;                           // 1
    unsigned int* eidx = (unsigned int*)(ovfn + 1);         // NBUCK*CAPB

    float* sum1 = stats,       *sumsq1 = stats + 32;
    float* sum2 = stats + 128, *sumsq2 = stats + 160;

    // zero stats + cnt + ovfn in one shot (contiguous)
    hipMemsetAsync(stats, 0, (256 + NBUCK + 1) * sizeof(int), stream);

    const int* src = edge_index;
    const int* dst = edge_index + N_EDGES;

    int nb = (N_NODES + 255) / 256;                // 391
    int bb = (N_EDGES + BIN_E - 1) / BIN_E;        // 391

    k_encode<<<nb, 256, 0, stream>>>(x_cont, x_cat, datanorm, W_cont, b_cont,
                                     emb_charge, emb_pdg, W_cat, b_cat, W_enc, b_enc,
                                     buf_emb, sum1, sumsq1);
    k_bin<<<bb, 1024, 0, stream>>>(src, dst, cnt, eidx, ovf, ovfn);
    k_normAB<<<nb, 256, 0, stream>>>(buf_emb, W_msg, g_all, be_all, sum1, sumsq1, buf_A, buf_B);
    k_fine<<<NBUCK, 512, 0, stream>>>(cnt, eidx, ovf, ovfn, buf_B, buf_A, b_msg, sum2, sumsq2);
    k_out<<<nb, 256, 0, stream>>>(buf_emb, buf_A, g_conv, be_conv, sum2, sumsq2,
                                  W_o1, b_o1, W_o2, b_o2, (float*)d_out);
}